// Round 10
// baseline (306.190 us; speedup 1.0000x reference)
//
#include <hip/hip_runtime.h>
#include <math.h>

typedef unsigned short u16;
typedef __attribute__((ext_vector_type(8))) short short8;
typedef __attribute__((ext_vector_type(4))) float f32x4;

#define MFMA16x16x32(a, b, c) __builtin_amdgcn_mfma_f32_16x16x32_bf16((a), (b), (c), 0, 0, 0)
#define GLL16(g, s)                                                        \
  __builtin_amdgcn_global_load_lds(                                        \
      (const __attribute__((address_space(1))) void*)(g),                  \
      (__attribute__((address_space(3))) void*)(s), 16, 0, 0)

__device__ __forceinline__ u16 f32_to_bf16(float x) {
  union { float f; unsigned u; } v; v.f = x;
  unsigned r = v.u + 0x7FFFu + ((v.u >> 16) & 1u);
  return (u16)(r >> 16);
}

__device__ __forceinline__ void cvt4(const float* in, u16* out, int j) {
  float4 v = ((const float4*)in)[j];
  ushort4 o;
  o.x = f32_to_bf16(v.x);
  o.y = f32_to_bf16(v.y);
  o.z = f32_to_bf16(v.z);
  o.w = f32_to_bf16(v.w);
  ((ushort4*)out)[j] = o;
}

// ---------------- fused fp32 -> bf16 converts ----------------
__global__ void cvt_all(const float* __restrict__ x, const float* __restrict__ wq,
                        const float* __restrict__ wo, u16* __restrict__ xb,
                        u16* __restrict__ wqb, u16* __restrict__ wob) {
  const int stride = gridDim.x * blockDim.x;
  const int i = blockIdx.x * blockDim.x + threadIdx.x;
  for (int j = i; j < 2097152; j += stride) cvt4(x, xb, j);
  for (int j = i; j < 3145728; j += stride) cvt4(wq, wqb, j);
  for (int j = i; j < 1048576; j += stride) cvt4(wo, wob, j);
}

// ======== m201-faithful 256x256 8-phase bf16 NT GEMM ========
// 8 waves (2M x 4N), wave-tile 128x64. LDS 128KB: As/Bs[2 buf][2 half][128x64].
// Iteration = 2 K-tiles (t0=2j -> buf0, t1=2j+1 -> buf1), 8 phases.
// Each phase: ds_reads -> stage 1 half-tile (2 GLL) -> barrier -> lgkm(0)
//             -> setprio(1)+16 MFMA+setprio(0) -> barrier.
// Stage order: ph0 A(t1)h0, ph1 A(t1)h1, ph2 B(t1+1)h0, ph3 B(t1+1)h1,
//              ph4 A(t1+1)h0, ph5 A(t1+1)h1, ph6 B(t1+2)h0, ph7 B(t1+2)h1.
// Gates: vmcnt(4) before closing barrier of ph3 and ph7 ONLY (vmcnt(0) at tail).
// RAW: needed tile's last GLL is always older than the newest 4 at each gate.
// WAR: each stage region's last reader drained >=1 barrier before the GLL issue.
template <int OUT_BF16>
__global__ __launch_bounds__(512, 2) void gemm_8ph(
    const u16* __restrict__ A,      // M x K row-major bf16
    const u16* __restrict__ B,      // N x K row-major bf16
    const float* __restrict__ bias, // length N
    void* __restrict__ C,           // M x N (bf16 or f32)
    int M, int N, int K, int gn)    // gn = grid cols (N/256)
{
  __shared__ __attribute__((aligned(16))) u16 As[2][2][8192];
  __shared__ __attribute__((aligned(16))) u16 Bs[2][2][8192];

  const int tid = threadIdx.x;
  const int w = tid >> 6, l = tid & 63;
  const int l15 = l & 15, l4 = l >> 4;
  const int wm = w >> 2, wn = w & 3;

  // XCD-bijective block swizzle (grid % 8 == 0)
  const int cpx = gridDim.x >> 3;
  const int sid = (blockIdx.x & 7) * cpx + (blockIdx.x >> 3);
  const long bm = (long)(sid / gn) * 256;
  const long bn = (long)(sid % gn) * 256;

  const int NT = K >> 6, NI = NT >> 1;

  // staging source (inverse-swizzled): LDS byte q of a half holds global
  // (row q>>7, colbyte (q&127)^((row&7)<<4)); lane covers q = tid*16 (+8192)
  const int r0 = tid >> 3;
  const int cb0 = ((tid * 16) & 127) ^ ((r0 & 7) << 4);
  const u16* aS = A + (bm + r0) * (long)K + (cb0 >> 1);
  const u16* bS = B + (bn + r0) * (long)K + (cb0 >> 1);
  const long rK64 = 64 * (long)K, rK128 = 128 * (long)K;
  const int ldst = w * 512;  // wave-uniform u16 dest within a half

#define STG(dstp, srcp, half, tt)                                            \
  do {                                                                       \
    GLL16((srcp) + (half) * rK128 + (long)(tt) * 64, (dstp) + ldst);         \
    GLL16((srcp) + (half) * rK128 + rK64 + (long)(tt) * 64,                  \
          (dstp) + ldst + 4096);                                             \
  } while (0)

  const f32x4 z4 = {0.f, 0.f, 0.f, 0.f};
  f32x4 acc[8][4];
  #pragma unroll
  for (int m = 0; m < 8; ++m)
    #pragma unroll
    for (int n = 0; n < 4; ++n) acc[m][n] = z4;

  const int swz = (l15 & 7) << 4;
  const int xo0 = (l4 * 16) ^ swz;
  const int xo1 = (64 + l4 * 16) ^ swz;
  const char* aRd0 = (const char*)&As[0][wm][0] + l15 * 128;
  const char* aRd1 = (const char*)&As[1][wm][0] + l15 * 128;
  const char* bRd0 = (const char*)&Bs[0][wn >> 1][0] + ((wn & 1) * 64 + l15) * 128;
  const char* bRd1 = (const char*)&Bs[1][wn >> 1][0] + ((wn & 1) * 64 + l15) * 128;

  // prologue: B0, A0, B1 (12 GLL); gate leaves B1's 4 in flight (steady state)
  STG(&Bs[0][0][0], bS, 0, 0);
  STG(&Bs[0][1][0], bS, 1, 0);
  STG(&As[0][0][0], aS, 0, 0);
  STG(&As[0][1][0], aS, 1, 0);
  STG(&Bs[1][0][0], bS, 0, 1);
  STG(&Bs[1][1][0], bS, 1, 1);
  asm volatile("s_waitcnt vmcnt(4)" ::: "memory");
  asm volatile("s_barrier" ::: "memory");

  for (int j = 0; j < NI; ++j) {
    const int t1 = 2 * j + 1;
    const bool more = (j + 1) < NI;
    short8 af[4][2], bf[4][2];

    // ===== ph0: af(m0-3) bf(n0-1) buf0; stage A(t1)h0 =====
    #pragma unroll
    for (int m = 0; m < 4; ++m) {
      af[m][0] = *(const short8*)(aRd0 + m * 2048 + xo0);
      af[m][1] = *(const short8*)(aRd0 + m * 2048 + xo1);
    }
    #pragma unroll
    for (int n = 0; n < 2; ++n) {
      bf[n][0] = *(const short8*)(bRd0 + n * 2048 + xo0);
      bf[n][1] = *(const short8*)(bRd0 + n * 2048 + xo1);
    }
    STG(&As[1][0][0], aS, 0, t1);
    asm volatile("s_barrier" ::: "memory");
    asm volatile("s_waitcnt lgkmcnt(0)" ::: "memory");
    __builtin_amdgcn_s_setprio(1);
    #pragma unroll
    for (int m = 0; m < 4; ++m)
      #pragma unroll
      for (int n = 0; n < 2; ++n) {
        acc[m][n] = MFMA16x16x32(af[m][0], bf[n][0], acc[m][n]);
        acc[m][n] = MFMA16x16x32(af[m][1], bf[n][1], acc[m][n]);
      }
    __builtin_amdgcn_s_setprio(0);
    asm volatile("s_barrier" ::: "memory");

    // ===== ph1: bf(n2-3) buf0; stage A(t1)h1 =====
    #pragma unroll
    for (int n = 2; n < 4; ++n) {
      bf[n][0] = *(const short8*)(bRd0 + n * 2048 + xo0);
      bf[n][1] = *(const short8*)(bRd0 + n * 2048 + xo1);
    }
    STG(&As[1][1][0], aS, 1, t1);
    asm volatile("s_barrier" ::: "memory");
    asm volatile("s_waitcnt lgkmcnt(0)" ::: "memory");
    __builtin_amdgcn_s_setprio(1);
    #pragma unroll
    for (int m = 0; m < 4; ++m)
      #pragma unroll
      for (int n = 2; n < 4; ++n) {
        acc[m][n] = MFMA16x16x32(af[m][0], bf[n][0], acc[m][n]);
        acc[m][n] = MFMA16x16x32(af[m][1], bf[n][1], acc[m][n]);
      }
    __builtin_amdgcn_s_setprio(0);
    asm volatile("s_barrier" ::: "memory");

    // ===== ph2: af(m4-7) buf0; stage B(t1+1)h0 =====
    #pragma unroll
    for (int m = 0; m < 4; ++m) {
      af[m][0] = *(const short8*)(aRd0 + 8192 + m * 2048 + xo0);
      af[m][1] = *(const short8*)(aRd0 + 8192 + m * 2048 + xo1);
    }
    if (more) STG(&Bs[0][0][0], bS, 0, t1 + 1);
    asm volatile("s_barrier" ::: "memory");
    asm volatile("s_waitcnt lgkmcnt(0)" ::: "memory");
    __builtin_amdgcn_s_setprio(1);
    #pragma unroll
    for (int m = 0; m < 4; ++m)
      #pragma unroll
      for (int n = 0; n < 2; ++n) {
        acc[4 + m][n] = MFMA16x16x32(af[m][0], bf[n][0], acc[4 + m][n]);
        acc[4 + m][n] = MFMA16x16x32(af[m][1], bf[n][1], acc[4 + m][n]);
      }
    __builtin_amdgcn_s_setprio(0);
    asm volatile("s_barrier" ::: "memory");

    // ===== ph3: stage B(t1+1)h1; gate t1 =====
    if (more) STG(&Bs[0][1][0], bS, 1, t1 + 1);
    asm volatile("s_barrier" ::: "memory");
    __builtin_amdgcn_s_setprio(1);
    #pragma unroll
    for (int m = 0; m < 4; ++m)
      #pragma unroll
      for (int n = 2; n < 4; ++n) {
        acc[4 + m][n] = MFMA16x16x32(af[m][0], bf[n][0], acc[4 + m][n]);
        acc[4 + m][n] = MFMA16x16x32(af[m][1], bf[n][1], acc[4 + m][n]);
      }
    __builtin_amdgcn_s_setprio(0);
    if (more) asm volatile("s_waitcnt vmcnt(4)" ::: "memory");
    else      asm volatile("s_waitcnt vmcnt(0)" ::: "memory");
    asm volatile("s_barrier" ::: "memory");

    // ===== ph4: af(m0-3) bf(n0-1) buf1; stage A(t1+1)h0 =====
    #pragma unroll
    for (int m = 0; m < 4; ++m) {
      af[m][0] = *(const short8*)(aRd1 + m * 2048 + xo0);
      af[m][1] = *(const short8*)(aRd1 + m * 2048 + xo1);
    }
    #pragma unroll
    for (int n = 0; n < 2; ++n) {
      bf[n][0] = *(const short8*)(bRd1 + n * 2048 + xo0);
      bf[n][1] = *(const short8*)(bRd1 + n * 2048 + xo1);
    }
    if (more) STG(&As[0][0][0], aS, 0, t1 + 1);
    asm volatile("s_barrier" ::: "memory");
    asm volatile("s_waitcnt lgkmcnt(0)" ::: "memory");
    __builtin_amdgcn_s_setprio(1);
    #pragma unroll
    for (int m = 0; m < 4; ++m)
      #pragma unroll
      for (int n = 0; n < 2; ++n) {
        acc[m][n] = MFMA16x16x32(af[m][0], bf[n][0], acc[m][n]);
        acc[m][n] = MFMA16x16x32(af[m][1], bf[n][1], acc[m][n]);
      }
    __builtin_amdgcn_s_setprio(0);
    asm volatile("s_barrier" ::: "memory");

    // ===== ph5: bf(n2-3) buf1; stage A(t1+1)h1 =====
    #pragma unroll
    for (int n = 2; n < 4; ++n) {
      bf[n][0] = *(const short8*)(bRd1 + n * 2048 + xo0);
      bf[n][1] = *(const short8*)(bRd1 + n * 2048 + xo1);
    }
    if (more) STG(&As[0][1][0], aS, 1, t1 + 1);
    asm volatile("s_barrier" ::: "memory");
    asm volatile("s_waitcnt lgkmcnt(0)" ::: "memory");
    __builtin_amdgcn_s_setprio(1);
    #pragma unroll
    for (int m = 0; m < 4; ++m)
      #pragma unroll
      for (int n = 2; n < 4; ++n) {
        acc[m][n] = MFMA16x16x32(af[m][0], bf[n][0], acc[m][n]);
        acc[m][n] = MFMA16x16x32(af[m][1], bf[n][1], acc[m][n]);
      }
    __builtin_amdgcn_s_setprio(0);
    asm volatile("s_barrier" ::: "memory");

    // ===== ph6: af(m4-7) buf1; stage B(t1+2)h0 =====
    #pragma unroll
    for (int m = 0; m < 4; ++m) {
      af[m][0] = *(const short8*)(aRd1 + 8192 + m * 2048 + xo0);
      af[m][1] = *(const short8*)(aRd1 + 8192 + m * 2048 + xo1);
    }
    if (more) STG(&Bs[1][0][0], bS, 0, t1 + 2);
    asm volatile("s_barrier" ::: "memory");
    asm volatile("s_waitcnt lgkmcnt(0)" ::: "memory");
    __builtin_amdgcn_s_setprio(1);
    #pragma unroll
    for (int m = 0; m < 4; ++m)
      #pragma unroll
      for (int n = 0; n < 2; ++n) {
        acc[4 + m][n] = MFMA16x16x32(af[m][0], bf[n][0], acc[4 + m][n]);
        acc[4 + m][n] = MFMA16x16x32(af[m][1], bf[n][1], acc[4 + m][n]);
      }
    __builtin_amdgcn_s_setprio(0);
    asm volatile("s_barrier" ::: "memory");

    // ===== ph7: stage B(t1+2)h1; gate next t0 =====
    if (more) STG(&Bs[1][1][0], bS, 1, t1 + 2);
    asm volatile("s_barrier" ::: "memory");
    __builtin_amdgcn_s_setprio(1);
    #pragma unroll
    for (int m = 0; m < 4; ++m)
      #pragma unroll
      for (int n = 2; n < 4; ++n) {
        acc[4 + m][n] = MFMA16x16x32(af[m][0], bf[n][0], acc[4 + m][n]);
        acc[4 + m][n] = MFMA16x16x32(af[m][1], bf[n][1], acc[4 + m][n]);
      }
    __builtin_amdgcn_s_setprio(0);
    if (more) {
      asm volatile("s_waitcnt vmcnt(4)" ::: "memory");
      asm volatile("s_barrier" ::: "memory");
    }
  }
#undef STG

  // ---- epilogue ----
  #pragma unroll
  for (int m = 0; m < 8; ++m) {
    const long row0 = bm + wm * 128 + m * 16 + l4 * 4;
    #pragma unroll
    for (int n = 0; n < 4; ++n) {
      const long col = bn + wn * 64 + n * 16 + l15;
      const float bv = bias[col];
      #pragma unroll
      for (int r = 0; r < 4; ++r) {
        const float v = acc[m][n][r] + bv;
        if (OUT_BF16)
          ((u16*)C)[(row0 + r) * (long)N + col] = f32_to_bf16(v);
        else
          ((float*)C)[(row0 + r) * (long)N + col] = v;
      }
    }
  }
}

// ======== 128x128 bf16 NT GEMM, BK=32, tribuf, 3 blocks/CU (out-proj) ========
template <int OUT_BF16>
__global__ __launch_bounds__(256, 3) void gemm_k32(
    const u16* __restrict__ A, const u16* __restrict__ B,
    const float* __restrict__ bias, void* __restrict__ C,
    int M, int N, int K)
{
  __shared__ u16 As[3][4096];
  __shared__ u16 Bs[3][4096];

  const int tid = threadIdx.x;
  const int w = tid >> 6, l = tid & 63;
  const int l15 = l & 15, l4 = l >> 4;
  const int wm = w >> 1, wn = w & 1;
  const long bm = (long)blockIdx.y * 128, bn = (long)blockIdx.x * 128;
  const int NT = K >> 5;

  const int h = (l & 7) ^ (l >> 3);
  const int rowoff = 2 * (l >> 3) + (h >> 2);
  const int colofs = (h & 3) * 8;
  const int c0 = (w & 1) * 4;
  const u16* sbase = (w < 2) ? (A + bm * (long)K) : (B + bn * (long)K);
  const u16* src0 = sbase + (long)(16 * (c0 + 0) + rowoff) * K + colofs;
  const u16* src1 = sbase + (long)(16 * (c0 + 1) + rowoff) * K + colofs;
  const u16* src2 = sbase + (long)(16 * (c0 + 2) + rowoff) * K + colofs;
  const u16* src3 = sbase + (long)(16 * (c0 + 3) + rowoff) * K + colofs;

#define STAGE4(tt)                                                            \
  do {                                                                        \
    const int _b = (tt) % 3;                                                  \
    const long _ko = (long)(tt) * 32;                                         \
    u16* _d = (w < 2) ? &As[_b][c0 * 512] : &Bs[_b][c0 * 512];                \
    GLL16(src0 + _ko, _d);                                                    \
    GLL16(src1 + _ko, _d + 512);                                              \
    GLL16(src2 + _ko, _d + 1024);                                             \
    GLL16(src3 + _ko, _d + 1536);                                             \
  } while (0)

  const f32x4 z4 = {0.f, 0.f, 0.f, 0.f};
  f32x4 acc[4][4];
  #pragma unroll
  for (int m = 0; m < 4; ++m)
    #pragma unroll
    for (int n = 0; n < 4; ++n) acc[m][n] = z4;

  const int inner = ((l15 & 1) * 64 + l4 * 16) ^ ((l15 >> 1) << 4);
  const int rbase = (l15 >> 1) * 128 + inner;
  const int aOfs = wm * 4096 + rbase;
  const int bOfs = wn * 4096 + rbase;

  STAGE4(0);
  STAGE4(1);
  asm volatile("s_waitcnt vmcnt(4)" ::: "memory");
  __builtin_amdgcn_s_barrier();

  for (int t = 0; t < NT; ++t) {
    const char* aT = (const char*)&As[t % 3][0];
    const char* bT = (const char*)&Bs[t % 3][0];
    short8 af[4], bf[4];
    #pragma unroll
    for (int m = 0; m < 4; ++m) af[m] = *(const short8*)(aT + aOfs + m * 1024);
    #pragma unroll
    for (int n = 0; n < 4; ++n) bf[n] = *(const short8*)(bT + bOfs + n * 1024);
    if (t + 2 < NT) {
      STAGE4(t + 2);
      asm volatile("s_waitcnt vmcnt(4) lgkmcnt(0)" ::: "memory");
    } else {
      asm volatile("s_waitcnt vmcnt(0) lgkmcnt(0)" ::: "memory");
    }
    __builtin_amdgcn_s_setprio(1);
    #pragma unroll
    for (int m = 0; m < 4; ++m)
      #pragma unroll
      for (int n = 0; n < 4; ++n)
        acc[m][n] = MFMA16x16x32(af[m], bf[n], acc[m][n]);
    __builtin_amdgcn_s_setprio(0);
    __builtin_amdgcn_s_barrier();
  }
#undef STAGE4

  #pragma unroll
  for (int m = 0; m < 4; ++m) {
    const long row0 = bm + wm * 64 + m * 16 + l4 * 4;
    #pragma unroll
    for (int n = 0; n < 4; ++n) {
      const long col = bn + wn * 64 + n * 16 + l15;
      const float bv = bias[col];
      #pragma unroll
      for (int r = 0; r < 4; ++r) {
        const float v = acc[m][n][r] + bv;
        if (OUT_BF16)
          ((u16*)C)[(row0 + r) * (long)N + col] = f32_to_bf16(v);
        else
          ((float*)C)[(row0 + r) * (long)N + col] = v;
      }
    }
  }
}

// ---------------- repack K and V into per-tile LDS images ----------------
__global__ __launch_bounds__(256) void repack_kv(
    const u16* __restrict__ qkv, u16* __restrict__ kimg, u16* __restrict__ vimg)
{
  const int t = blockIdx.x;
  const int h = blockIdx.y, b = blockIdx.z;
  const int tid = threadIdx.x;
  __shared__ u16 Vl[64][136];

  const long qbase = ((long)(b * 2048 + t * 64)) * 6144 + h * 128;
  u16* kout = kimg + (((long)(b * 16 + h) * 32 + t) * 8192);
  u16* vout = vimg + (((long)(b * 16 + h) * 32 + t) * 8192);

  #pragma unroll
  for (int i = 0; i < 4; ++i) {
    const int j = tid + i * 256;
    {
      const int r = j >> 4, c8 = (j & 15) * 8;
      uint4 v = *(const uint4*)(qkv + qbase + (long)r * 6144 + 4096 + c8);
      *(uint4*)(&Vl[r][c8]) = v;
    }
    {
      const int byte = j * 16;
      const int r = byte >> 8;
      const int wv = (byte & 255) ^ ((r & 7) << 4);
      const int d0 = wv >> 1;
      uint4 v = *(const uint4*)(qkv + qbase + (long)r * 6144 + 2048 + d0);
      *(uint4*)(kout + j * 8) = v;
    }
  }
  __syncthreads();
  #pragma unroll
  for (int i = 0; i < 4; ++i) {
    const int j = tid + i * 256;
    const int byte = j * 16;
    const int d = byte >> 7;
    const int wv = (byte & 127) ^ ((d & 7) << 4);
    const int k0 = wv >> 1;
    u16 tmp[8];
    #pragma unroll
    for (int m = 0; m < 8; ++m) tmp[m] = Vl[k0 + m][d];
    *(uint4*)(vout + j * 8) = *(const uint4*)tmp;
  }
}

// ---------------- flash causal attention with alibi ----------------
__global__ __launch_bounds__(256) void attn_kernel(
    const u16* __restrict__ qkv,
    const u16* __restrict__ kimg,
    const u16* __restrict__ vimg,
    u16* __restrict__ ctx)
{
  const int S = 2048, NHD = 6144, NT = 32;
  const int p = blockIdx.x, h = blockIdx.y, b = blockIdx.z;
  const int tid = threadIdx.x;
  const int w = tid >> 6, l = tid & 63;
  const int l15 = l & 15, l4 = l >> 4;

  __shared__ u16 Ks[64 * 128];
  __shared__ u16 Vt[128 * 64];
  __shared__ u16 Ps[4][16 * 64];

  const float LOG2E = 1.44269504088896f;
  const float c1 = 0.08838834764831845f * LOG2E;
  const float slope2 = exp2f(-0.5f * (float)(h + 1)) * LOG2E;

  const f32x4 z4 = {0.f, 0.f, 0.f, 0.f};

  for (int pass = 0; pass < 2; ++pass) {
    const int qblk = pass ? (NT - 1 - p) : p;
    const int qb0 = qblk * 64;

    short8 qf[4];
    {
      const int qrow = qb0 + w * 16 + l15;
      const u16* qp = qkv + (long)(b * S + qrow) * NHD + h * 128 + l4 * 8;
      #pragma unroll
      for (int kc = 0; kc < 4; ++kc) qf[kc] = *(const short8*)(qp + kc * 32);
    }

    f32x4 o[8];
    #pragma unroll
    for (int i = 0; i < 8; ++i) o[i] = z4;
    float m_r[4] = {-3.0e38f, -3.0e38f, -3.0e38f, -3.0e38f};
    float l_r[4] = {0.f, 0.f, 0.f, 0.f};

    for (int kt = 0; kt <= qblk; ++kt) {
      const u16* ksrc = kimg + (((long)(b * 16 + h) * NT + kt) * 8192);
      const u16* vsrc = vimg + (((long)(b * 16 + h) * NT + kt) * 8192);
      #pragma unroll
      for (int i = 0; i < 4; ++i) {
        const int chunk = w * 4 + i;
        __builtin_amdgcn_global_load_lds(
            (const __attribute__((address_space(1))) void*)(ksrc + chunk * 512 + l * 8),
            (__attribute__((address_space(3))) void*)(Ks + chunk * 512), 16, 0, 0);
        __builtin_amdgcn_global_load_lds(
            (const __attribute__((address_space(1))) void*)(vsrc + chunk * 512 + l * 8),
            (__attribute__((address_space(3))) void*)(Vt + chunk * 512), 16, 0, 0);
      }
      __syncthreads();

      // ---- QK^T ----
      f32x4 sf[4];
      #pragma unroll
      for (int nt = 0; nt < 4; ++nt) sf[nt] = z4;
      #pragma unroll
      for (int nt = 0; nt < 4; ++nt) {
        const int krow = nt * 16 + l15;
        #pragma unroll
        for (int kc = 0; kc < 4; ++kc) {
          int kbyte = (krow * 256 + kc * 64 + l4 * 16) ^ ((krow & 7) << 4);
          const short8 kf = *(const short8*)((const char*)Ks + kbyte);
          sf[nt] = MFMA16x16x32(qf[kc], kf, sf[nt]);
        }
      }

      // ---- online softmax: interleaved shuffle reductions ----
      float add_nt[4];
      int kg_nt[4];
      #pragma unroll
      for (int nt = 0; nt < 4; ++nt) {
        kg_nt[nt] = kt * 64 + nt * 16 + l15;
        add_nt[nt] = slope2 * (float)(kg_nt[nt] - (S - 1));
      }
      const bool diag = (kt == qblk);
      float sc[4][4], mxv[4];
      #pragma unroll
      for (int r = 0; r < 4; ++r) {
        const int qg = qb0 + w * 16 + l4 * 4 + r;
        #pragma unroll
        for (int nt = 0; nt < 4; ++nt) {
          float s = sf[nt][r] * c1 + add_nt[nt];
          if (diag && kg_nt[nt] > qg) s = -3.0e38f;
          sc[r][nt] = s;
        }
        mxv[r] = fmaxf(fmaxf(sc[r][0], sc[r][1]), fmaxf(sc[r][2], sc[r][3]));
      }
      #pragma unroll
      for (int d = 1; d < 16; d <<= 1) {
        #pragma unroll
        for (int r = 0; r < 4; ++r)
          mxv[r] = fmaxf(mxv[r], __shfl_xor(mxv[r], d, 64));
      }
      float alpha[4], sum[4];
      #pragma unroll
      for (int r = 0; r < 4; ++r) {
        const float mnew = fmaxf(m_r[r], mxv[r]);
        sum[r] = 0.f;
        #pragma unroll
        for (int nt = 0; nt < 4; ++nt) {
          const float pv = exp2f(sc[r][nt] - mnew);
          sc[r][nt] = pv;
          sum[r] += pv;
        }
        alpha[r] = exp2f(m_r[r] - mnew);
        m_r[r] = mnew;
      }
      #pragma unroll
      for (int d = 1; d < 16; d <<= 1) {
        #pragma unroll
        for (int r = 0; r < 4; ++r) sum[r] += __shfl_xor(sum[r], d, 64);
      }
      #pragma unroll
      for (int r = 0; r < 4; ++r) l_r[r] = l_r[r] * alpha[r] + sum[r];

      #pragma unroll
      for (int r = 0; r < 4; ++r) {
        const int qrow_l = l4 * 4 + r;
        #pragma unroll
        for (int nt = 0; nt < 4; ++nt) {
          int pbyte = ((qrow_l * 64 + nt * 16 + l15) * 2) ^ ((qrow_l & 7) << 4);
          *(u16*)((char*)&Ps[w][0] + pbyte) = f32_to_bf16(sc[r][nt]);
        }
      }

      #pragma unroll
      for (int nt = 0; nt < 8; ++nt)
        #pragma unroll
        for (int r = 0; r < 4; ++r) o[nt][r] *= alpha[r];

      #pragma unroll
      for (int kc = 0; kc < 2; ++kc) {
        int pbyte = ((l15 * 64 + kc * 32 + l4 * 8) * 2) ^ ((l15 & 7) << 4);
        const short8 pf = *(const short8*)((const char*)&Ps[w][0] + pbyte);
        #pragma unroll
        for (int nt = 0; nt < 8; ++nt) {
          const int d = nt * 16 + l15;
          const int vbyte = ((d * 128 + kc * 64 + l4 * 16)) ^ ((d & 7) << 4);
          const short8 vf = *(const short8*)((const char*)Vt + vbyte);
          o[nt] = MFMA16x16x32(pf, vf, o[nt]);
        }
      }
      __syncthreads();
    }

    float rl[4];
    #pragma unroll
    for (int r = 0; r < 4; ++r) rl[r] = 1.0f / l_r[r];
    #pragma unroll
    for (int nt = 0; nt < 8; ++nt) {
      #pragma unroll
      for (int r = 0; r < 4; ++r) {
        const int qg = qb0 + w * 16 + l4 * 4 + r;
        ctx[(long)(b * S + qg) * 2048 + h * 128 + nt * 16 + l15] =
            f32_to_bf16(o[nt][r] * rl[r]);
      }
    }
  }
}

// ---------------- launch ----------------
extern "C" void kernel_launch(void* const* d_in, const int* in_sizes, int n_in,
                              void* d_out, int out_size, void* d_ws, size_t ws_size,
                              hipStream_t stream) {
  const float* x     = (const float*)d_in[0];
  const float* w_qkv = (const float*)d_in[2];
  const float* b_qkv = (const float*)d_in[3];
  const float* w_out = (const float*)d_in[4];
  const float* b_out = (const float*)d_in[5];
  float* out = (float*)d_out;

  // B=2, S=2048, D=2048, H=16, hd=128
  char* ws = (char*)d_ws;
  u16* xb    = (u16*)(ws);                     // 4096x2048   (16.8 MB) dead after GEMM1
  u16* wqkvb = (u16*)(ws + 16777216UL);        // 6144x2048   (25.2 MB) dead after GEMM1
  u16* woutb = (u16*)(ws + 41943040UL);        // 2048x2048   ( 8.4 MB)
  u16* qkvb  = (u16*)(ws + 50331648UL);        // 4096x6144   (50.3 MB)
  u16* ctxb  = (u16*)(ws + 100663296UL);       // 4096x2048   (16.8 MB)
  u16* kimg  = (u16*)(ws);                     // 16.8 MB (overlays xb)
  u16* vimg  = (u16*)(ws + 16777216UL);        // 16.8 MB (overlays wqkvb)

  cvt_all<<<2048, 256, 0, stream>>>(x, w_qkv, w_out, xb, wqkvb, woutb);

  gemm_8ph<1><<<384, 512, 0, stream>>>(xb, wqkvb, b_qkv, (void*)qkvb, 4096, 6144, 2048, 24);

  repack_kv<<<dim3(32, 16, 2), 256, 0, stream>>>(qkvb, kimg, vimg);

  attn_kernel<<<dim3(16, 16, 2), 256, 0, stream>>>(qkvb, kimg, vimg, ctxb);

  gemm_k32<0><<<dim3(16, 32), 256, 0, stream>>>(ctxb, woutb, b_out, (void*)out, 4096, 2048, 2048);
}

// Round 11
// 293.662 us; speedup vs baseline: 1.0427x; 1.0427x over previous
//
#include <hip/hip_runtime.h>
#include <math.h>

typedef unsigned short u16;
typedef __attribute__((ext_vector_type(8))) short short8;
typedef __attribute__((ext_vector_type(4))) float f32x4;

#define MFMA16x16x32(a, b, c) __builtin_amdgcn_mfma_f32_16x16x32_bf16((a), (b), (c), 0, 0, 0)
#define GLL16(g, s)                                                        \
  __builtin_amdgcn_global_load_lds(                                        \
      (const __attribute__((address_space(1))) void*)(g),                  \
      (__attribute__((address_space(3))) void*)(s), 16, 0, 0)

__device__ __forceinline__ u16 f32_to_bf16(float x) {
  union { float f; unsigned u; } v; v.f = x;
  unsigned r = v.u + 0x7FFFu + ((v.u >> 16) & 1u);
  return (u16)(r >> 16);
}

__device__ __forceinline__ void cvt4(const float* in, u16* out, int j) {
  float4 v = ((const float4*)in)[j];
  ushort4 o;
  o.x = f32_to_bf16(v.x);
  o.y = f32_to_bf16(v.y);
  o.z = f32_to_bf16(v.z);
  o.w = f32_to_bf16(v.w);
  ((ushort4*)out)[j] = o;
}

// ---------------- fused fp32 -> bf16 converts ----------------
__global__ void cvt_all(const float* __restrict__ x, const float* __restrict__ wq,
                        const float* __restrict__ wo, u16* __restrict__ xb,
                        u16* __restrict__ wqb, u16* __restrict__ wob) {
  const int stride = gridDim.x * blockDim.x;
  const int i = blockIdx.x * blockDim.x + threadIdx.x;
  for (int j = i; j < 2097152; j += stride) cvt4(x, xb, j);
  for (int j = i; j < 3145728; j += stride) cvt4(wq, wqb, j);
  for (int j = i; j < 1048576; j += stride) cvt4(wo, wob, j);
}

// ======== 128x256 bf16 NT GEMM, 2-phase counted-vmcnt pipeline (R8 best) ========
// 8 waves (2M x 4N), per-wave 64x64. A dbuf 2x16KB, B tribuf 3x32KB = 128KB.
template <int OUT_BF16>
__global__ __launch_bounds__(512, 2) void gemm_nt_p2(
    const u16* __restrict__ A,      // M x K row-major bf16
    const u16* __restrict__ B,      // N x K row-major bf16
    const float* __restrict__ bias, // length N
    void* __restrict__ C,           // M x N (bf16 or f32)
    int M, int N, int K)
{
  __shared__ u16 As[2][8192];    // [buf][128 x 64] swizzled
  __shared__ u16 Bs[3][16384];   // [buf][2 halves x 128 x 64] swizzled

  const int tid = threadIdx.x;
  const int w = tid >> 6, l = tid & 63;
  const int l15 = l & 15, l4 = l >> 4;
  const int wm = w >> 2, wn = w & 3;
  const long bm = (long)blockIdx.y * 128, bn = (long)blockIdx.x * 256;
  const int NT = K >> 6;

  const u16 *aSrc0, *aSrc1, *bSrc0, *bSrc1;
  {
    int q = w * 2048 + l * 16;
    int r = q >> 7, cb = (q & 127) ^ ((r & 7) << 4);
    aSrc0 = A + (bm + r) * (long)K + (cb >> 1);
    bSrc0 = B + (bn + r) * (long)K + (cb >> 1);
    q += 1024;
    r = q >> 7; cb = (q & 127) ^ ((r & 7) << 4);
    aSrc1 = A + (bm + r) * (long)K + (cb >> 1);
    bSrc1 = B + (bn + r) * (long)K + (cb >> 1);
  }
  const long bHS = 128 * (long)K;
  const int ldst = w * 1024;

#define STAGE6(tt)                                                            \
  do {                                                                        \
    const long ko = (long)(tt) * 64;                                          \
    const int vb = (tt) % 3, ab = (tt) & 1;                                   \
    GLL16(aSrc0 + ko, &As[ab][ldst]);                                         \
    GLL16(aSrc1 + ko, &As[ab][ldst + 512]);                                   \
    GLL16(bSrc0 + ko, &Bs[vb][ldst]);                                         \
    GLL16(bSrc1 + ko, &Bs[vb][ldst + 512]);                                   \
    GLL16(bSrc0 + bHS + ko, &Bs[vb][8192 + ldst]);                            \
    GLL16(bSrc1 + bHS + ko, &Bs[vb][8192 + ldst + 512]);                      \
  } while (0)

  const f32x4 z4 = {0.f, 0.f, 0.f, 0.f};
  f32x4 acc[4][4];
  #pragma unroll
  for (int m = 0; m < 4; ++m)
    #pragma unroll
    for (int n = 0; n < 4; ++n) acc[m][n] = z4;

  const int xo0 = (l4 * 16) ^ ((l15 & 7) << 4);
  const int xo1 = (64 + l4 * 16) ^ ((l15 & 7) << 4);

  short8 af[4][2], bf[4][2];

  STAGE6(0);
  STAGE6(1);
  asm volatile("s_waitcnt vmcnt(6)\ns_barrier" ::: "memory");

  for (int t = 0; t < NT; ++t) {
    const char* ab = (const char*)&As[t & 1][0] + (wm * 64 + l15) * 128;
    const char* bb = (const char*)&Bs[t % 3][0] + (wn * 32 + l15) * 128;

    #pragma unroll
    for (int m = 0; m < 4; ++m) {
      af[m][0] = *(const short8*)(ab + m * 2048 + xo0);
      af[m][1] = *(const short8*)(ab + m * 2048 + xo1);
    }
    #pragma unroll
    for (int n = 0; n < 2; ++n) {
      bf[n][0] = *(const short8*)(bb + n * 2048 + xo0);
      bf[n][1] = *(const short8*)(bb + n * 2048 + xo1);
    }
    asm volatile("s_waitcnt lgkmcnt(0)" ::: "memory");
    __builtin_amdgcn_s_setprio(1);
    #pragma unroll
    for (int m = 0; m < 4; ++m)
      #pragma unroll
      for (int n = 0; n < 2; ++n) {
        acc[m][n] = MFMA16x16x32(af[m][0], bf[n][0], acc[m][n]);
        acc[m][n] = MFMA16x16x32(af[m][1], bf[n][1], acc[m][n]);
      }
    __builtin_amdgcn_s_setprio(0);
    asm volatile("s_barrier" ::: "memory");

    #pragma unroll
    for (int n = 0; n < 2; ++n) {
      bf[2 + n][0] = *(const short8*)(bb + 16384 + n * 2048 + xo0);
      bf[2 + n][1] = *(const short8*)(bb + 16384 + n * 2048 + xo1);
    }
    if (t + 2 < NT) STAGE6(t + 2);
    if (t >= NT - 2)
      asm volatile("s_waitcnt vmcnt(0) lgkmcnt(0)" ::: "memory");
    else
      asm volatile("s_waitcnt vmcnt(6) lgkmcnt(0)" ::: "memory");
    __builtin_amdgcn_s_setprio(1);
    #pragma unroll
    for (int m = 0; m < 4; ++m)
      #pragma unroll
      for (int n = 2; n < 4; ++n) {
        acc[m][n] = MFMA16x16x32(af[m][0], bf[n][0], acc[m][n]);
        acc[m][n] = MFMA16x16x32(af[m][1], bf[n][1], acc[m][n]);
      }
    __builtin_amdgcn_s_setprio(0);
    asm volatile("s_barrier" ::: "memory");
  }
#undef STAGE6

  #pragma unroll
  for (int m = 0; m < 4; ++m) {
    const long row0 = bm + wm * 64 + m * 16 + l4 * 4;
    #pragma unroll
    for (int n = 0; n < 4; ++n) {
      const long col = bn + wn * 32 + (n & 1) * 16 + (n >> 1) * 128 + l15;
      const float bv = bias[col];
      #pragma unroll
      for (int r = 0; r < 4; ++r) {
        const float v = acc[m][n][r] + bv;
        if (OUT_BF16)
          ((u16*)C)[(row0 + r) * (long)N + col] = f32_to_bf16(v);
        else
          ((float*)C)[(row0 + r) * (long)N + col] = v;
      }
    }
  }
}

// ---------------- repack K and V into per-tile LDS images ----------------
__global__ __launch_bounds__(256) void repack_kv(
    const u16* __restrict__ qkv, u16* __restrict__ kimg, u16* __restrict__ vimg)
{
  const int t = blockIdx.x;
  const int h = blockIdx.y, b = blockIdx.z;
  const int tid = threadIdx.x;
  __shared__ u16 Vl[64][136];

  const long qbase = ((long)(b * 2048 + t * 64)) * 6144 + h * 128;
  u16* kout = kimg + (((long)(b * 16 + h) * 32 + t) * 8192);
  u16* vout = vimg + (((long)(b * 16 + h) * 32 + t) * 8192);

  #pragma unroll
  for (int i = 0; i < 4; ++i) {
    const int j = tid + i * 256;
    {
      const int r = j >> 4, c8 = (j & 15) * 8;
      uint4 v = *(const uint4*)(qkv + qbase + (long)r * 6144 + 4096 + c8);
      *(uint4*)(&Vl[r][c8]) = v;
    }
    {
      const int byte = j * 16;
      const int r = byte >> 8;
      const int wv = (byte & 255) ^ ((r & 7) << 4);
      const int d0 = wv >> 1;
      uint4 v = *(const uint4*)(qkv + qbase + (long)r * 6144 + 2048 + d0);
      *(uint4*)(kout + j * 8) = v;
    }
  }
  __syncthreads();
  #pragma unroll
  for (int i = 0; i < 4; ++i) {
    const int j = tid + i * 256;
    const int byte = j * 16;
    const int d = byte >> 7;
    const int wv = (byte & 127) ^ ((d & 7) << 4);
    const int k0 = wv >> 1;
    u16 tmp[8];
    #pragma unroll
    for (int m = 0; m < 8; ++m) tmp[m] = Vl[k0 + m][d];
    *(uint4*)(vout + j * 8) = *(const uint4*)tmp;
  }
}

// ---------------- flash causal attention, QBLK=128, dbuf staged K/V ----------------
// grid (8,16,2), 512 threads (8 waves). Block p handles q-supers P=p and 15-p
// (128 q-rows each); per pass, kv tiles 0..2P+1 -> 34 tiles/block constant.
// Per tile: issue STAGE(kt+1) -> compute(kt) -> __syncthreads() (drains vmcnt).
__global__ __launch_bounds__(512) void attn_kernel(
    const u16* __restrict__ qkv,
    const u16* __restrict__ kimg,
    const u16* __restrict__ vimg,
    u16* __restrict__ ctx)
{
  const int S = 2048, NHD = 6144;
  const int p = blockIdx.x, h = blockIdx.y, b = blockIdx.z;
  const int tid = threadIdx.x;
  const int w = tid >> 6, l = tid & 63;
  const int l15 = l & 15, l4 = l >> 4;

  __shared__ u16 Kd[2][8192];   // [buf][64 x 128] swizzled image
  __shared__ u16 Vd[2][8192];   // [buf][128 x 64] transposed swizzled image
  __shared__ u16 Ps[8][1024];   // per-wave P (16x64), swizzled

  const float LOG2E = 1.44269504088896f;
  const float c1 = 0.08838834764831845f * LOG2E;
  const float slope2 = exp2f(-0.5f * (float)(h + 1)) * LOG2E;

  const long ibase = ((long)(b * 16 + h) * 32) * 8192;
  const u16* kbase = kimg + ibase;
  const u16* vbase = vimg + ibase;

#define ASTAGE(kt, buf)                                                       \
  do {                                                                        \
    const u16* _ks = kbase + (long)(kt) * 8192;                               \
    const u16* _vs = vbase + (long)(kt) * 8192;                               \
    _Pragma("unroll")                                                         \
    for (int _i = 0; _i < 2; ++_i) {                                          \
      const int _c = w * 2 + _i;                                              \
      GLL16(_ks + _c * 512 + l * 8, &Kd[buf][_c * 512]);                      \
      GLL16(_vs + _c * 512 + l * 8, &Vd[buf][_c * 512]);                      \
    }                                                                         \
  } while (0)

  const f32x4 z4 = {0.f, 0.f, 0.f, 0.f};

  for (int pass = 0; pass < 2; ++pass) {
    const int Q = pass ? (15 - p) : p;
    const int qb0 = Q * 128;
    const int NTkv = 2 * Q + 2;

    short8 qf[4];
    {
      const int qrow = qb0 + w * 16 + l15;
      const u16* qp = qkv + (long)(b * S + qrow) * NHD + h * 128 + l4 * 8;
      #pragma unroll
      for (int kc = 0; kc < 4; ++kc) qf[kc] = *(const short8*)(qp + kc * 32);
    }

    f32x4 o[8];
    #pragma unroll
    for (int i = 0; i < 8; ++i) o[i] = z4;
    float m_r[4] = {-3.0e38f, -3.0e38f, -3.0e38f, -3.0e38f};
    float l_r[4] = {0.f, 0.f, 0.f, 0.f};

    ASTAGE(0, 0);
    __syncthreads();

    for (int kt = 0; kt < NTkv; ++kt) {
      if (kt + 1 < NTkv) ASTAGE(kt + 1, (kt + 1) & 1);
      const int cb = kt & 1;
      const char* Kc = (const char*)&Kd[cb][0];
      const char* Vc = (const char*)&Vd[cb][0];

      // ---- QK^T ----
      f32x4 sf[4];
      #pragma unroll
      for (int nt = 0; nt < 4; ++nt) sf[nt] = z4;
      #pragma unroll
      for (int nt = 0; nt < 4; ++nt) {
        const int krow = nt * 16 + l15;
        #pragma unroll
        for (int kc = 0; kc < 4; ++kc) {
          int kbyte = (krow * 256 + kc * 64 + l4 * 16) ^ ((krow & 7) << 4);
          const short8 kf = *(const short8*)(Kc + kbyte);
          sf[nt] = MFMA16x16x32(qf[kc], kf, sf[nt]);
        }
      }

      // ---- online softmax (unconditional causal mask) ----
      float add_nt[4];
      int kg_nt[4];
      #pragma unroll
      for (int nt = 0; nt < 4; ++nt) {
        kg_nt[nt] = kt * 64 + nt * 16 + l15;
        add_nt[nt] = slope2 * (float)(kg_nt[nt] - (S - 1));
      }
      float sc[4][4], mxv[4];
      #pragma unroll
      for (int r = 0; r < 4; ++r) {
        const int qg = qb0 + w * 16 + l4 * 4 + r;
        #pragma unroll
        for (int nt = 0; nt < 4; ++nt) {
          float s = sf[nt][r] * c1 + add_nt[nt];
          if (kg_nt[nt] > qg) s = -3.0e38f;
          sc[r][nt] = s;
        }
        mxv[r] = fmaxf(fmaxf(sc[r][0], sc[r][1]), fmaxf(sc[r][2], sc[r][3]));
      }
      #pragma unroll
      for (int d = 1; d < 16; d <<= 1) {
        #pragma unroll
        for (int r = 0; r < 4; ++r)
          mxv[r] = fmaxf(mxv[r], __shfl_xor(mxv[r], d, 64));
      }
      float alpha[4], sum[4];
      #pragma unroll
      for (int r = 0; r < 4; ++r) {
        const float mnew = fmaxf(m_r[r], mxv[r]);
        sum[r] = 0.f;
        #pragma unroll
        for (int nt = 0; nt < 4; ++nt) {
          const float pv = exp2f(sc[r][nt] - mnew);
          sc[r][nt] = pv;
          sum[r] += pv;
        }
        alpha[r] = exp2f(m_r[r] - mnew);
        m_r[r] = mnew;
      }
      #pragma unroll
      for (int d = 1; d < 16; d <<= 1) {
        #pragma unroll
        for (int r = 0; r < 4; ++r) sum[r] += __shfl_xor(sum[r], d, 64);
      }
      #pragma unroll
      for (int r = 0; r < 4; ++r) l_r[r] = l_r[r] * alpha[r] + sum[r];

      // ---- write P (bf16) to per-wave LDS, swizzled ----
      #pragma unroll
      for (int r = 0; r < 4; ++r) {
        const int qrow_l = l4 * 4 + r;
        #pragma unroll
        for (int nt = 0; nt < 4; ++nt) {
          int pbyte = ((qrow_l * 64 + nt * 16 + l15) * 2) ^ ((qrow_l & 7) << 4);
          *(u16*)((char*)&Ps[w][0] + pbyte) = f32_to_bf16(sc[r][nt]);
        }
      }

      // ---- rescale O, then PV ----
      #pragma unroll
      for (int nt = 0; nt < 8; ++nt)
        #pragma unroll
        for (int r = 0; r < 4; ++r) o[nt][r] *= alpha[r];

      #pragma unroll
      for (int kc = 0; kc < 2; ++kc) {
        int pbyte = ((l15 * 64 + kc * 32 + l4 * 8) * 2) ^ ((l15 & 7) << 4);
        const short8 pf = *(const short8*)((const char*)&Ps[w][0] + pbyte);
        #pragma unroll
        for (int nt = 0; nt < 8; ++nt) {
          const int d = nt * 16 + l15;
          const int vbyte = ((d * 128 + kc * 64 + l4 * 16)) ^ ((d & 7) << 4);
          const short8 vf = *(const short8*)(Vc + vbyte);
          o[nt] = MFMA16x16x32(pf, vf, o[nt]);
        }
      }
      __syncthreads();  // drains vmcnt(0): STAGE(kt+1) landed; buffers safe
    }

    float rl[4];
    #pragma unroll
    for (int r = 0; r < 4; ++r) rl[r] = 1.0f / l_r[r];
    #pragma unroll
    for (int nt = 0; nt < 8; ++nt) {
      #pragma unroll
      for (int r = 0; r < 4; ++r) {
        const int qg = qb0 + w * 16 + l4 * 4 + r;
        ctx[(long)(b * S + qg) * 2048 + h * 128 + nt * 16 + l15] =
            f32_to_bf16(o[nt][r] * rl[r]);
      }
    }
    __syncthreads();  // pass-boundary: all reads done before next pass restages
  }
#undef ASTAGE
}

// ---------------- launch ----------------
extern "C" void kernel_launch(void* const* d_in, const int* in_sizes, int n_in,
                              void* d_out, int out_size, void* d_ws, size_t ws_size,
                              hipStream_t stream) {
  const float* x     = (const float*)d_in[0];
  const float* w_qkv = (const float*)d_in[2];
  const float* b_qkv = (const float*)d_in[3];
  const float* w_out = (const float*)d_in[4];
  const float* b_out = (const float*)d_in[5];
  float* out = (float*)d_out;

  // B=2, S=2048, D=2048, H=16, hd=128
  char* ws = (char*)d_ws;
  u16* xb    = (u16*)(ws);                     // 4096x2048   (16.8 MB) dead after GEMM1
  u16* wqkvb = (u16*)(ws + 16777216UL);        // 6144x2048   (25.2 MB) dead after GEMM1
  u16* woutb = (u16*)(ws + 41943040UL);        // 2048x2048   ( 8.4 MB)
  u16* qkvb  = (u16*)(ws + 50331648UL);        // 4096x6144   (50.3 MB)
  u16* ctxb  = (u16*)(ws + 100663296UL);       // 4096x2048   (16.8 MB)
  u16* kimg  = (u16*)(ws);                     // 16.8 MB (overlays xb)
  u16* vimg  = (u16*)(ws + 16777216UL);        // 16.8 MB (overlays wqkvb)

  cvt_all<<<2048, 256, 0, stream>>>(x, w_qkv, w_out, xb, wqkvb, woutb);

  gemm_nt_p2<1><<<dim3(24, 32), 512, 0, stream>>>(xb, wqkvb, b_qkv, (void*)qkvb, 4096, 6144, 2048);

  repack_kv<<<dim3(32, 16, 2), 256, 0, stream>>>(qkvb, kimg, vimg);

  attn_kernel<<<dim3(8, 16, 2), 512, 0, stream>>>(qkvb, kimg, vimg, ctxb);

  gemm_nt_p2<0><<<dim3(8, 32), 512, 0, stream>>>(ctxb, woutb, b_out, (void*)out, 4096, 2048, 2048);
}